// Round 5
// baseline (136.658 us; speedup 1.0000x reference)
//
#include <hip/hip_runtime.h>
#include <hip/hip_bf16.h>

typedef __bf16 bf16;
typedef __bf16 bf16x8 __attribute__((ext_vector_type(8)));
typedef float f32x4 __attribute__((ext_vector_type(4)));

#define MFMA_16x16x32(A, B, C) __builtin_amdgcn_mfma_f32_16x16x32_bf16(A, B, C, 0, 0, 0)

static_assert(sizeof(bf16x8) == 16, "bf16x8 must be 16B");

// ---------------------------------------------------------------------------
// Kernel 0: cast + transpose the three weight matrices to bf16:
//   Wt[p][h][c] = W_p[c][h],  p in {q,k,v}, h<64, c<1024.
// ---------------------------------------------------------------------------
__global__ __launch_bounds__(256) void wtrans_kernel(
    const float* __restrict__ Wq, const float* __restrict__ Wk,
    const float* __restrict__ Wv, bf16* __restrict__ Wt)
{
  int idx = blockIdx.x * 256 + threadIdx.x;   // 3*64*1024 = 196608 total
  int p = idx >> 16;
  int rem = idx & 65535;
  int h = rem >> 10;
  int c = rem & 1023;
  const float* W = (p == 0) ? Wq : (p == 1) ? Wk : Wv;
  Wt[idx] = (bf16)W[c * 64 + h];
}

// ---------------------------------------------------------------------------
// Kernel 1: projections — register-staged (T14) 2-phase GEMM.
//   blockIdx.y == 0 : Q = q @ Wq
//   blockIdx.y == 1 : K = k @ Wk, V = k @ Wv  (V stored transposed)
// BM=64, BK=32, 256 thr (4 waves x 16 rows). Global loads go to REGISTERS
// (coalesced float4 for A, bf16x8 for B), issued 2-3 tiles ahead in two
// named ping-pong sets (static indexing, no scratch); f32->bf16 convert +
// explicit ds_write_b128 into 80B-padded LDS (pad spreads bank quads for
// both write and read). Outstanding loads live in per-wave vmcnt queues
// (not the shared LDS-DMA engine) — the m13-proven 6.3 TB/s path.
// LDS 30KB, grid 1024 blocks = 4 blocks/CU = 16 waves/CU.
// ---------------------------------------------------------------------------
__global__ __launch_bounds__(256) void proj_kernel(
    const float* __restrict__ qin, const float* __restrict__ kin,
    const bf16* __restrict__ Wt,
    bf16* __restrict__ Qb, bf16* __restrict__ Kb, bf16* __restrict__ Vtb)
{
  const int p = blockIdx.y;              // 0: Q   1: K+V
  const int m0 = blockIdx.x * 64;
  const float* A = (p == 0) ? qin : kin;

  // 40 bf16 = 80 B row stride: bank-quad = (5*row + chunk) mod 8 -> spread
  __shared__ __align__(16) bf16 As[2][64][40];        // 2 x 5 KB
  __shared__ __align__(16) bf16 Bs[2][2][64][40];     // 2 x 2 x 5 KB

  const int tid = threadIdx.x;
  const int lane = tid & 63;
  const int w = tid >> 6;
  const int g = lane >> 4;
  const int r = lane & 15;

  // staging geometry: thread owns (row = tid>>2, chunk = tid&3) of each tile
  const int srow = tid >> 2;
  const int sch  = tid & 3;
  const float* agp = A + (size_t)(m0 + srow) * 1024 + sch * 8;
  const bf16*  b0p = Wt + (size_t)((p == 0) ? 0 : 1) * 65536 + (size_t)srow * 1024 + sch * 8;
  const bf16*  b1p = Wt + (size_t)2 * 65536 + (size_t)srow * 1024 + sch * 8;

  f32x4 acc0[4], acc1[4];
  #pragma unroll
  for (int cf = 0; cf < 4; cf++) {
    acc0[cf] = (f32x4){0.f, 0.f, 0.f, 0.f};
    acc1[cf] = (f32x4){0.f, 0.f, 0.f, 0.f};
  }

  // two named register staging sets (static indexing — rule #20)
  float4 rAa0, rAb0, rAa1, rAb1;
  bf16x8 rB00, rB01, rB10, rB11;

#define ISSUE(SET, K0)                                                        \
  do {                                                                        \
    rAa##SET = *(const float4*)(agp + (K0));                                  \
    rAb##SET = *(const float4*)(agp + (K0) + 4);                              \
    rB0##SET = *(const bf16x8*)(b0p + (K0));                                  \
    if (p == 1) rB1##SET = *(const bf16x8*)(b1p + (K0));                      \
  } while (0)

#define WSTAGE(BUF, SET)                                                      \
  do {                                                                        \
    bf16x8 av = (bf16x8){                                                     \
        (bf16)rAa##SET.x, (bf16)rAa##SET.y, (bf16)rAa##SET.z,                 \
        (bf16)rAa##SET.w, (bf16)rAb##SET.x, (bf16)rAb##SET.y,                 \
        (bf16)rAb##SET.z, (bf16)rAb##SET.w};                                  \
    *(bf16x8*)&As[BUF][srow][sch * 8] = av;                                   \
    *(bf16x8*)&Bs[BUF][0][srow][sch * 8] = rB0##SET;                          \
    if (p == 1) *(bf16x8*)&Bs[BUF][1][srow][sch * 8] = rB1##SET;              \
  } while (0)

  // one K-step: 1 A ds_read + 8 B ds_reads + 8 (p=1) / 4 (p=0) MFMAs
  auto compute = [&](int buf) {
    bf16x8 af = *(const bf16x8*)&As[buf][w * 16 + r][g * 8];
    #pragma unroll
    for (int cf = 0; cf < 4; cf++) {
      bf16x8 bf0 = *(const bf16x8*)&Bs[buf][0][cf * 16 + r][g * 8];
      acc0[cf] = MFMA_16x16x32(af, bf0, acc0[cf]);
    }
    if (p == 1) {
      #pragma unroll
      for (int cf = 0; cf < 4; cf++) {
        bf16x8 bf1 = *(const bf16x8*)&Bs[buf][1][cf * 16 + r][g * 8];
        acc1[cf] = MFMA_16x16x32(af, bf1, acc1[cf]);
      }
    }
  };

  // --- prologue: buf0=t0, buf1=t1, set0 = t2 in flight ---
  ISSUE(0, 0);
  ISSUE(1, 32);
  WSTAGE(0, 0);          // compiler inserts counted vmcnt for set0 here
  ISSUE(0, 64);          // set0 <- tile 2
  WSTAGE(1, 1);          // tile 1
  __syncthreads();

  // invariant at loop top: buf0 = tile t, buf1 = t+1, set0 = t+2, set1 free
  for (int j = 0; j < 16; ++j) {
    const int t = 2 * j;
    if (t + 3 < 32) ISSUE(1, (t + 3) * 32);   // set1 <- t+3 (issue early)
    compute(0);                                // tile t
    __syncthreads();                           // all done reading buf0
    if (t + 2 < 32) WSTAGE(0, 0);              // buf0 <- tile t+2
    __syncthreads();                           // writes visible
    if (t + 4 < 32) ISSUE(0, (t + 4) * 32);   // set0 <- t+4
    compute(1);                                // tile t+1
    __syncthreads();
    if (t + 3 < 32) WSTAGE(1, 1);              // buf1 <- tile t+3
    __syncthreads();
  }

#undef ISSUE
#undef WSTAGE

  // --- epilogue: C/D layout row=(l>>4)*4+j, col=l&15 ---
  #pragma unroll
  for (int cf = 0; cf < 4; cf++) {
    #pragma unroll
    for (int jj = 0; jj < 4; jj++) {
      int rg = m0 + w * 16 + g * 4 + jj;
      int col = cf * 16 + r;
      if (p == 0) {
        Qb[(size_t)rg * 64 + col] = (bf16)acc0[cf][jj];
      } else {
        Kb[(size_t)rg * 64 + col] = (bf16)acc0[cf][jj];
        int bb = rg >> 11, t2 = rg & 2047;
        Vtb[(size_t)(bb * 64 + col) * 2048 + t2] = (bf16)acc1[cf][jj];
      }
    }
  }
}

// ---------------------------------------------------------------------------
// Kernel 2: causal flash attention (unchanged).
// Block = 256 threads (4 waves). Q-block = 64 rows (16 per wave), KV tile=64.
// ---------------------------------------------------------------------------
__global__ __launch_bounds__(256) void attn_kernel(
    const bf16* __restrict__ Qb, const bf16* __restrict__ Kb,
    const bf16* __restrict__ Vtb, float* __restrict__ out)
{
  const int qt = (int)(gridDim.x - 1 - blockIdx.x);   // heavy blocks first
  const int b = blockIdx.y;
  const int tid = threadIdx.x;
  const int lane = tid & 63;
  const int w = tid >> 6;
  const int g = lane >> 4;
  const int r = lane & 15;

  __shared__ __align__(16) bf16 Ks[64][80];
  __shared__ __align__(16) bf16 Vs[64][80];
  __shared__ __align__(16) bf16 Ps[4][16][80];

  const int q0 = qt * 64 + w * 16;   // wave's first q-row
  const bf16* qp = Qb + (size_t)(b * 2048 + q0 + r) * 64 + g * 8;
  const bf16x8 qf0 = *(const bf16x8*)qp;
  const bf16x8 qf1 = *(const bf16x8*)(qp + 32);

  f32x4 acc_o[4];
  #pragma unroll
  for (int hf = 0; hf < 4; hf++) acc_o[hf] = (f32x4){0.f, 0.f, 0.f, 0.f};
  float m_r[4] = {-1e30f, -1e30f, -1e30f, -1e30f};
  float l_r[4] = {0.f, 0.f, 0.f, 0.f};
  const float scale = 0.03125f;   // 1/sqrt(1024)

  const int sh = tid >> 2;
  const int sc = (tid & 3) * 16;

  for (int kv = 0; kv <= qt; kv++) {
    // --- stage K tile [64 s][64 h] and V^T tile [64 h][64 s] ---
    {
      const bf16* kp = Kb + (size_t)(b * 2048 + kv * 64 + sh) * 64 + sc;
      *(bf16x8*)&Ks[sh][sc]     = *(const bf16x8*)kp;
      *(bf16x8*)&Ks[sh][sc + 8] = *(const bf16x8*)(kp + 8);
      const bf16* vp = Vtb + (size_t)(b * 64 + sh) * 2048 + kv * 64 + sc;
      *(bf16x8*)&Vs[sh][sc]     = *(const bf16x8*)vp;
      *(bf16x8*)&Vs[sh][sc + 8] = *(const bf16x8*)(vp + 8);
    }
    __syncthreads();

    // --- S = Q K^T : 16x64 per wave ---
    f32x4 s[4];
    #pragma unroll
    for (int cf = 0; cf < 4; cf++) {
      bf16x8 kf0 = *(const bf16x8*)&Ks[cf * 16 + r][g * 8];
      bf16x8 kf1 = *(const bf16x8*)&Ks[cf * 16 + r][32 + g * 8];
      f32x4 t = (f32x4){0.f, 0.f, 0.f, 0.f};
      t = MFMA_16x16x32(qf0, kf0, t);
      t = MFMA_16x16x32(qf1, kf1, t);
      s[cf] = t;
    }

    // --- scale + causal mask + online softmax ---
    const bool diag = (kv == qt);
    float pm[4] = {-1e30f, -1e30f, -1e30f, -1e30f};
    #pragma unroll
    for (int cf = 0; cf < 4; cf++) {
      #pragma unroll
      for (int j = 0; j < 4; j++) {
        float v = s[cf][j] * scale;
        if (diag && (cf * 16 + r) > (w * 16 + g * 4 + j)) v = -1e30f;
        s[cf][j] = v;
        pm[j] = fmaxf(pm[j], v);
      }
    }
    #pragma unroll
    for (int j = 0; j < 4; j++) {
      #pragma unroll
      for (int msk = 1; msk < 16; msk <<= 1)
        pm[j] = fmaxf(pm[j], __shfl_xor(pm[j], msk, 64));
    }
    float corr[4];
    #pragma unroll
    for (int j = 0; j < 4; j++) {
      float mn = fmaxf(m_r[j], pm[j]);
      corr[j] = __expf(m_r[j] - mn);
      m_r[j] = mn;
    }
    float rs[4] = {0.f, 0.f, 0.f, 0.f};
    #pragma unroll
    for (int cf = 0; cf < 4; cf++) {
      #pragma unroll
      for (int j = 0; j < 4; j++) {
        float pv = __expf(s[cf][j] - m_r[j]);
        s[cf][j] = pv;
        rs[j] += pv;
      }
    }
    #pragma unroll
    for (int j = 0; j < 4; j++) {
      #pragma unroll
      for (int msk = 1; msk < 16; msk <<= 1)
        rs[j] += __shfl_xor(rs[j], msk, 64);
      l_r[j] = l_r[j] * corr[j] + rs[j];
    }
    #pragma unroll
    for (int hf = 0; hf < 4; hf++)
      #pragma unroll
      for (int j = 0; j < 4; j++)
        acc_o[hf][j] *= corr[j];

    // --- P (C-layout) -> LDS -> A-layout fragments ---
    #pragma unroll
    for (int cf = 0; cf < 4; cf++)
      #pragma unroll
      for (int j = 0; j < 4; j++)
        Ps[w][g * 4 + j][cf * 16 + r] = (bf16)s[cf][j];

    __syncthreads();

    // --- O += P V ---
    #pragma unroll
    for (int ss = 0; ss < 2; ss++) {
      bf16x8 pf = *(const bf16x8*)&Ps[w][r][ss * 32 + g * 8];
      #pragma unroll
      for (int hf = 0; hf < 4; hf++) {
        bf16x8 vf = *(const bf16x8*)&Vs[hf * 16 + r][ss * 32 + g * 8];
        acc_o[hf] = MFMA_16x16x32(pf, vf, acc_o[hf]);
      }
    }
    __syncthreads();   // before next tile's staging overwrites Ks/Vs
  }

  // --- epilogue: divide by softmax denom, write f32 ---
  float inv[4];
  #pragma unroll
  for (int j = 0; j < 4; j++) inv[j] = 1.0f / l_r[j];
  const size_t ob = (size_t)(b * 2048 + q0) * 64;
  #pragma unroll
  for (int hf = 0; hf < 4; hf++)
    #pragma unroll
    for (int j = 0; j < 4; j++)
      out[ob + (size_t)(g * 4 + j) * 64 + hf * 16 + r] = acc_o[hf][j] * inv[j];
}

// ---------------------------------------------------------------------------
extern "C" void kernel_launch(void* const* d_in, const int* in_sizes, int n_in,
                              void* d_out, int out_size, void* d_ws, size_t ws_size,
                              hipStream_t stream)
{
  const float* q  = (const float*)d_in[0];
  const float* k  = (const float*)d_in[1];
  const float* Wq = (const float*)d_in[2];
  const float* Wk = (const float*)d_in[3];
  const float* Wv = (const float*)d_in[4];
  float* out = (float*)d_out;

  char* ws = (char*)d_ws;
  bf16* Qb  = (bf16*)(ws);                      // [16*2048][64] bf16, 4MB
  bf16* Kb  = (bf16*)(ws + (4u << 20));         // [16*2048][64] bf16, 4MB
  bf16* Vtb = (bf16*)(ws + (8u << 20));         // [16][64][2048] bf16, 4MB
  bf16* Wt  = (bf16*)(ws + (12u << 20));        // [3][64][1024] bf16, 384KB

  hipLaunchKernelGGL(wtrans_kernel, dim3(768), dim3(256), 0, stream,
                     Wq, Wk, Wv, Wt);
  hipLaunchKernelGGL(proj_kernel, dim3(512, 2), dim3(256), 0, stream,
                     q, k, Wt, Qb, Kb, Vtb);
  hipLaunchKernelGGL(attn_kernel, dim3(32, 16), dim3(256), 0, stream,
                     Qb, Kb, Vtb, out);
}